// Round 1
// baseline (124.872 us; speedup 1.0000x reference)
//
#include <hip/hip_runtime.h>

#define NN 2048
#define FF 64
#define HH 16
#define OO 8

// ---------------- Kernel 1: per-feature f-MLP partials ----------------
// grid (FF, NN/256), block 256. Each block: one feature f, 256 nodes.
// Writes part[(n*FF+f)*OO + o].
__global__ __launch_bounds__(256) void fnet_kernel(
    const float* __restrict__ x,
    const float* __restrict__ fW1, const float* __restrict__ fb1,
    const float* __restrict__ fW2, const float* __restrict__ fb2,
    const float* __restrict__ fW3, const float* __restrict__ fb3,
    float* __restrict__ part)
{
    __shared__ float sw1[HH], sb1[HH], sw2[HH * HH], sb2[HH], sw3[OO * HH], sb3[OO];
    const int f = blockIdx.x;
    const int tid = threadIdx.x;

    if (tid < HH) {
        sw1[tid] = fW1[f * HH + tid];
        sb1[tid] = fb1[f * HH + tid];
        sb2[tid] = fb2[f * HH + tid];
    }
    if (tid < HH * HH) sw2[tid] = fW2[f * HH * HH + tid];
    if (tid < OO * HH) sw3[tid] = fW3[f * OO * HH + tid];
    if (tid < OO)      sb3[tid] = fb3[f * OO + tid];
    __syncthreads();

    const int n = blockIdx.y * 256 + tid;
    const float xv = x[n * FF + f];

    float h1[HH];
#pragma unroll
    for (int h = 0; h < HH; ++h)
        h1[h] = fmaxf(xv * sw1[h] + sb1[h], 0.f);

    float h2[HH];
#pragma unroll
    for (int g = 0; g < HH; ++g) {
        float a = sb2[g];
#pragma unroll
        for (int h = 0; h < HH; ++h) a += sw2[g * HH + h] * h1[h];
        h2[g] = fmaxf(a, 0.f);
    }

#pragma unroll
    for (int o = 0; o < OO; ++o) {
        float a = sb3[o];
#pragma unroll
        for (int h = 0; h < HH; ++h) a += sw3[o * HH + h] * h2[h];
        part[(n * FF + f) * OO + o] = a;
    }
}

// ---------------- Kernel 2: reduce partials over F ----------------
// grid NN, block 64 (one wave). Lane f reads part[(n*FF+f)*OO..+7].
__global__ __launch_bounds__(64) void fsum_reduce(
    const float* __restrict__ part, float* __restrict__ f_sums)
{
    const int n = blockIdx.x;
    const int f = threadIdx.x;
    const float4* p = reinterpret_cast<const float4*>(part + (n * FF + f) * OO);
    float4 a = p[0];
    float4 b = p[1];
#pragma unroll
    for (int off = 32; off > 0; off >>= 1) {
        a.x += __shfl_down(a.x, off, 64);
        a.y += __shfl_down(a.y, off, 64);
        a.z += __shfl_down(a.z, off, 64);
        a.w += __shfl_down(a.w, off, 64);
        b.x += __shfl_down(b.x, off, 64);
        b.y += __shfl_down(b.y, off, 64);
        b.z += __shfl_down(b.z, off, 64);
        b.w += __shfl_down(b.w, off, 64);
    }
    if (f == 0) {
        float4* q = reinterpret_cast<float4*>(f_sums + n * OO);
        q[0] = a;
        q[1] = b;
    }
}

// ---------------- Kernel 3: m-MLP + normalize + matvec ----------------
// grid NN (one block per row i), block 256. Each thread handles 8 j's.
__global__ __launch_bounds__(256) void mnet_kernel(
    const float* __restrict__ d, const float* __restrict__ norm,
    const float* __restrict__ f_sums,
    const float* __restrict__ mW1, const float* __restrict__ mb1,
    const float* __restrict__ mW2, const float* __restrict__ mb2,
    const float* __restrict__ mW3, const float* __restrict__ mb3,
    float* __restrict__ out)
{
    __shared__ float sw1[HH], sb1[HH], sw2[HH * HH], sb2[HH], sw3[HH];
    __shared__ float red[4][OO];
    const int i = blockIdx.x;
    const int tid = threadIdx.x;

    if (tid < HH) {
        sw1[tid] = mW1[tid];
        sb1[tid] = mb1[tid];
        sb2[tid] = mb2[tid];
        sw3[tid] = mW3[tid];
    }
    if (tid < HH * HH) sw2[tid] = mW2[tid];
    __syncthreads();

    const float b3 = mb3[0];

    float acc[OO];
#pragma unroll
    for (int o = 0; o < OO; ++o) acc[o] = 0.f;

    const float* drow = d + (size_t)i * NN;
    const float* nrow = norm + (size_t)i * NN;

    for (int jj = 0; jj < NN; jj += 256) {
        const int j = jj + tid;
        const float dv = drow[j];
        const float nv = nrow[j];

        float h1[HH];
#pragma unroll
        for (int h = 0; h < HH; ++h)
            h1[h] = fmaxf(dv * sw1[h] + sb1[h], 0.f);

        float h2[HH];
#pragma unroll
        for (int g = 0; g < HH; ++g) {
            float a = sb2[g];
#pragma unroll
            for (int h = 0; h < HH; ++h) a += sw2[g * HH + h] * h1[h];
            h2[g] = fmaxf(a, 0.f);
        }

        float m = b3;
#pragma unroll
        for (int h = 0; h < HH; ++h) m += sw3[h] * h2[h];

        const float mn = m / nv;

        const float4* fs = reinterpret_cast<const float4*>(f_sums + j * OO);
        const float4 f0 = fs[0];
        const float4 f1 = fs[1];
        acc[0] += mn * f0.x; acc[1] += mn * f0.y;
        acc[2] += mn * f0.z; acc[3] += mn * f0.w;
        acc[4] += mn * f1.x; acc[5] += mn * f1.y;
        acc[6] += mn * f1.z; acc[7] += mn * f1.w;
    }

    // wave-level reduce
#pragma unroll
    for (int off = 32; off > 0; off >>= 1) {
#pragma unroll
        for (int o = 0; o < OO; ++o) acc[o] += __shfl_down(acc[o], off, 64);
    }
    const int wave = tid >> 6;
    const int lane = tid & 63;
    if (lane == 0) {
#pragma unroll
        for (int o = 0; o < OO; ++o) red[wave][o] = acc[o];
    }
    __syncthreads();
    if (tid == 0) {
#pragma unroll
        for (int o = 0; o < OO; ++o)
            out[i * OO + o] = red[0][o] + red[1][o] + red[2][o] + red[3][o];
    }
}

extern "C" void kernel_launch(void* const* d_in, const int* in_sizes, int n_in,
                              void* d_out, int out_size, void* d_ws, size_t ws_size,
                              hipStream_t stream)
{
    const float* x   = (const float*)d_in[0];
    const float* nd  = (const float*)d_in[1];
    const float* nm  = (const float*)d_in[2];
    const float* fW1 = (const float*)d_in[3];
    const float* fb1 = (const float*)d_in[4];
    const float* fW2 = (const float*)d_in[5];
    const float* fb2 = (const float*)d_in[6];
    const float* fW3 = (const float*)d_in[7];
    const float* fb3 = (const float*)d_in[8];
    const float* mW1 = (const float*)d_in[9];
    const float* mb1 = (const float*)d_in[10];
    const float* mW2 = (const float*)d_in[11];
    const float* mb2 = (const float*)d_in[12];
    const float* mW3 = (const float*)d_in[13];
    const float* mb3 = (const float*)d_in[14];
    float* out = (float*)d_out;

    float* part   = (float*)d_ws;                 // NN*FF*OO floats = 4 MiB
    float* f_sums = part + (size_t)NN * FF * OO;  // NN*OO floats

    fnet_kernel<<<dim3(FF, NN / 256), 256, 0, stream>>>(
        x, fW1, fb1, fW2, fb2, fW3, fb3, part);
    fsum_reduce<<<NN, 64, 0, stream>>>(part, f_sums);
    mnet_kernel<<<NN, 256, 0, stream>>>(
        nd, nm, f_sums, mW1, mb1, mW2, mb2, mW3, mb3, out);
}

// Round 2
// 51.373 us; speedup vs baseline: 2.4307x; 2.4307x over previous
//
#include <hip/hip_runtime.h>

#define NN 2048
#define FF 64
#define HH 16
#define OO 8

#define BIGF  1e30f
#define BIGTH 1e29f
#define MAXBP 288   // 16 L1 knees + 17*16 layer-2 crossings
#define BPPAD 512   // power-of-2 padded breakpoint array
#define ABPAD 320   // alpha/beta arrays (segments 0..288)

// ---------- helpers: propagate (slope,intercept) through frozen ReLU pattern ----------
__device__ inline void l1_pattern(float c, const float* w1, const float* b1,
                                  float* a1, float* v1)
{
#pragma unroll
    for (int h = 0; h < HH; ++h) {
        const float arg = fmaf(w1[h], c, b1[h]);
        const bool act = arg > 0.f;
        a1[h] = act ? w1[h] : 0.f;
        v1[h] = act ? b1[h] : 0.f;
    }
}

__device__ inline void l2_arg(float c, int g,
                              const float* w1, const float* b1,
                              const float* w2, const float* b2,
                              float& A, float& B)
{
    float a1[HH], v1[HH];
    l1_pattern(c, w1, b1, a1, v1);
    float Aa = 0.f, Bb = b2[g];
#pragma unroll
    for (int h = 0; h < HH; ++h) {
        Aa = fmaf(w2[g * HH + h], a1[h], Aa);
        Bb = fmaf(w2[g * HH + h], v1[h], Bb);
    }
    A = Aa; B = Bb;
}

__device__ inline void pwl_coeffs(float c,
                                  const float* w1, const float* b1,
                                  const float* w2, const float* b2,
                                  const float* w3, float b3,
                                  float& alpha, float& beta)
{
    float a1[HH], v1[HH];
    l1_pattern(c, w1, b1, a1, v1);
    float al = 0.f, be = b3;
#pragma unroll
    for (int g = 0; g < HH; ++g) {
        float A = 0.f, B = b2[g];
#pragma unroll
        for (int h = 0; h < HH; ++h) {
            A = fmaf(w2[g * HH + h], a1[h], A);
            B = fmaf(w2[g * HH + h], v1[h], B);
        }
        const bool act = fmaf(A, c, B) > 0.f;
        al = fmaf(w3[g], act ? A : 0.f, al);
        be = fmaf(w3[g], act ? B : 0.f, be);
    }
    alpha = al; beta = be;
}

__device__ inline float seg_midpoint(float L, float R)
{
    float c;
    if (L <= -BIGTH && R >= BIGTH) c = 2.5f;
    else if (L <= -BIGTH)          c = R - 1.f;
    else if (R >= BIGTH)           c = L + 1.f;
    else                           c = 0.5f * (L + R);
    return fminf(fmaxf(c, -20.f), 20.f);
}

// ---------------- Kernel 0: build exact PWL representation of m(d) ----------------
// one block, 512 threads. Outputs: bp[512] sorted breakpoints (BIG-padded),
// ab[0..319]=alpha, ab[320..639]=beta for segments s = count(bp <= d).
__global__ __launch_bounds__(512) void pwl_setup(
    const float* __restrict__ mW1, const float* __restrict__ mb1,
    const float* __restrict__ mW2, const float* __restrict__ mb2,
    const float* __restrict__ mW3, const float* __restrict__ mb3,
    float* __restrict__ bp_out, float* __restrict__ ab_out)
{
    __shared__ float w1[HH], b1[HH], w2[HH * HH], b2[HH], w3[HH];
    __shared__ float b3s;
    __shared__ float ends[18];
    __shared__ float cand[MAXBP];
    __shared__ float sorted[MAXBP];
    __shared__ float t16s[HH];
    const int tid = threadIdx.x;

    if (tid < HH) { w1[tid] = mW1[tid]; b1[tid] = mb1[tid]; b2[tid] = mb2[tid]; w3[tid] = mW3[tid]; }
    if (tid < HH * HH) w2[tid] = mW2[tid];
    if (tid == 0) b3s = mb3[0];
    __syncthreads();

    // --- layer-1 knees t_h = -b1/w1, valid iff finite and within (-10,10) ---
    if (tid < HH) {
        const float w = w1[tid];
        const float t = -b1[tid] / w;
        cand[tid] = (w != 0.f && t > -10.f && t < 10.f) ? t : BIGF;
    }
    __syncthreads();
    // sort the 16 L1 knees (rank sort)
    if (tid < HH) {
        const float my = cand[tid];
        int r = 0;
        for (int k = 0; k < HH; ++k) {
            const float o = cand[k];
            r += (o < my) || (o == my && k < tid);
        }
        t16s[r] = my;
    }
    __syncthreads();
    if (tid == 0)  ends[0] = -BIGF;
    if (tid < HH)  ends[tid + 1] = t16s[tid];
    if (tid == 0)  ends[17] = BIGF;
    __syncthreads();

    // --- layer-2 zero crossings within each L1 interval ---
    if (tid < 17 * HH) {
        const int iv = tid >> 4;
        const int g  = tid & 15;
        const float L = ends[iv], R = ends[iv + 1];
        float x = BIGF;
        if (L < BIGTH) {
            const float c = seg_midpoint(L, R);
            float A, B;
            l2_arg(c, g, w1, b1, w2, b2, A, B);
            const float xx = -B / A;
            if (xx > L && xx < R && xx > -10.f && xx < 10.f) x = xx;
        }
        cand[HH + tid] = x;
    }
    __syncthreads();

    // --- global rank-sort of all 288 candidates (BIG = invalid, sorts last) ---
    if (tid < MAXBP) {
        const float my = cand[tid];
        int r = 0;
        for (int k = 0; k < MAXBP; ++k) {
            const float o = cand[k];
            r += (o < my) || (o == my && k < tid);
        }
        sorted[r] = my;
    }
    __syncthreads();

    // --- emit padded breakpoint array ---
    bp_out[tid] = (tid < MAXBP) ? sorted[tid] : BIGF;

    // --- per-segment (alpha,beta) via pattern propagation at segment midpoint ---
    if (tid < ABPAD) {
        float al = 0.f, be = 0.f;
        if (tid <= MAXBP) {
            const float L = (tid == 0)     ? -BIGF : sorted[tid - 1];
            const float R = (tid < MAXBP)  ? sorted[tid] : BIGF;
            const float c = seg_midpoint(L, R);
            pwl_coeffs(c, w1, b1, w2, b2, w3, b3s, al, be);
        }
        ab_out[tid] = al;
        ab_out[ABPAD + tid] = be;
    }
}

// ---------------- Kernel 1: per-feature f-MLP partials ----------------
__global__ __launch_bounds__(256) void fnet_kernel(
    const float* __restrict__ x,
    const float* __restrict__ fW1, const float* __restrict__ fb1,
    const float* __restrict__ fW2, const float* __restrict__ fb2,
    const float* __restrict__ fW3, const float* __restrict__ fb3,
    float* __restrict__ part)
{
    __shared__ float sw1[HH], sb1[HH], sw2[HH * HH], sb2[HH], sw3[OO * HH], sb3[OO];
    const int f = blockIdx.x;
    const int tid = threadIdx.x;

    if (tid < HH) {
        sw1[tid] = fW1[f * HH + tid];
        sb1[tid] = fb1[f * HH + tid];
        sb2[tid] = fb2[f * HH + tid];
    }
    if (tid < HH * HH) sw2[tid] = fW2[f * HH * HH + tid];
    if (tid < OO * HH) sw3[tid] = fW3[f * OO * HH + tid];
    if (tid < OO)      sb3[tid] = fb3[f * OO + tid];
    __syncthreads();

    const int n = blockIdx.y * 256 + tid;
    const float xv = x[n * FF + f];

    float h1[HH];
#pragma unroll
    for (int h = 0; h < HH; ++h)
        h1[h] = fmaxf(xv * sw1[h] + sb1[h], 0.f);

    float h2[HH];
#pragma unroll
    for (int g = 0; g < HH; ++g) {
        float a = sb2[g];
#pragma unroll
        for (int h = 0; h < HH; ++h) a += sw2[g * HH + h] * h1[h];
        h2[g] = fmaxf(a, 0.f);
    }

#pragma unroll
    for (int o = 0; o < OO; ++o) {
        float a = sb3[o];
#pragma unroll
        for (int h = 0; h < HH; ++h) a += sw3[o * HH + h] * h2[h];
        part[(n * FF + f) * OO + o] = a;
    }
}

// ---------------- Kernel 2: reduce partials over F ----------------
__global__ __launch_bounds__(64) void fsum_reduce(
    const float* __restrict__ part, float* __restrict__ f_sums)
{
    const int n = blockIdx.x;
    const int f = threadIdx.x;
    const float4* p = reinterpret_cast<const float4*>(part + (n * FF + f) * OO);
    float4 a = p[0];
    float4 b = p[1];
#pragma unroll
    for (int off = 32; off > 0; off >>= 1) {
        a.x += __shfl_down(a.x, off, 64);
        a.y += __shfl_down(a.y, off, 64);
        a.z += __shfl_down(a.z, off, 64);
        a.w += __shfl_down(a.w, off, 64);
        b.x += __shfl_down(b.x, off, 64);
        b.y += __shfl_down(b.y, off, 64);
        b.z += __shfl_down(b.z, off, 64);
        b.w += __shfl_down(b.w, off, 64);
    }
    if (f == 0) {
        float4* q = reinterpret_cast<float4*>(f_sums + n * OO);
        q[0] = a;
        q[1] = b;
    }
}

// ---------------- Kernel 3: PWL m + normalize + matvec ----------------
__global__ __launch_bounds__(256) void mnet_pwl(
    const float* __restrict__ d, const float* __restrict__ norm,
    const float* __restrict__ f_sums,
    const float* __restrict__ bp_g, const float* __restrict__ ab_g,
    float* __restrict__ out)
{
    __shared__ float sbp[BPPAD];
    __shared__ float sal[ABPAD], sbe[ABPAD];
    __shared__ float red[4][OO];
    const int i = blockIdx.x;
    const int tid = threadIdx.x;

    for (int k = tid; k < BPPAD; k += 256) sbp[k] = bp_g[k];
    for (int k = tid; k < ABPAD; k += 256) { sal[k] = ab_g[k]; sbe[k] = ab_g[ABPAD + k]; }
    __syncthreads();

    float acc[OO];
#pragma unroll
    for (int o = 0; o < OO; ++o) acc[o] = 0.f;

    const float* drow = d + (size_t)i * NN;
    const float* nrow = norm + (size_t)i * NN;

#pragma unroll
    for (int ch = 0; ch < 2; ++ch) {
        const int j0 = ch * 1024 + (tid << 2);
        const float4 dv4 = *reinterpret_cast<const float4*>(drow + j0);
        const float4 nv4 = *reinterpret_cast<const float4*>(nrow + j0);
        const float dvs[4] = {dv4.x, dv4.y, dv4.z, dv4.w};
        const float nvs[4] = {nv4.x, nv4.y, nv4.z, nv4.w};
#pragma unroll
        for (int e = 0; e < 4; ++e) {
            const float dv = dvs[e];
            int lo = 0;
#pragma unroll
            for (int st = 256; st >= 1; st >>= 1)
                lo += (sbp[lo + st - 1] <= dv) ? st : 0;
            const float mn = fmaf(sal[lo], dv, sbe[lo]) / nvs[e];
            const float4 f0 = *reinterpret_cast<const float4*>(f_sums + (j0 + e) * OO);
            const float4 f1 = *reinterpret_cast<const float4*>(f_sums + (j0 + e) * OO + 4);
            acc[0] = fmaf(mn, f0.x, acc[0]);
            acc[1] = fmaf(mn, f0.y, acc[1]);
            acc[2] = fmaf(mn, f0.z, acc[2]);
            acc[3] = fmaf(mn, f0.w, acc[3]);
            acc[4] = fmaf(mn, f1.x, acc[4]);
            acc[5] = fmaf(mn, f1.y, acc[5]);
            acc[6] = fmaf(mn, f1.z, acc[6]);
            acc[7] = fmaf(mn, f1.w, acc[7]);
        }
    }

#pragma unroll
    for (int off = 32; off > 0; off >>= 1) {
#pragma unroll
        for (int o = 0; o < OO; ++o) acc[o] += __shfl_down(acc[o], off, 64);
    }
    const int wave = tid >> 6;
    const int lane = tid & 63;
    if (lane == 0) {
#pragma unroll
        for (int o = 0; o < OO; ++o) red[wave][o] = acc[o];
    }
    __syncthreads();
    if (tid == 0) {
#pragma unroll
        for (int o = 0; o < OO; ++o)
            out[i * OO + o] = red[0][o] + red[1][o] + red[2][o] + red[3][o];
    }
}

extern "C" void kernel_launch(void* const* d_in, const int* in_sizes, int n_in,
                              void* d_out, int out_size, void* d_ws, size_t ws_size,
                              hipStream_t stream)
{
    const float* x   = (const float*)d_in[0];
    const float* nd  = (const float*)d_in[1];
    const float* nm  = (const float*)d_in[2];
    const float* fW1 = (const float*)d_in[3];
    const float* fb1 = (const float*)d_in[4];
    const float* fW2 = (const float*)d_in[5];
    const float* fb2 = (const float*)d_in[6];
    const float* fW3 = (const float*)d_in[7];
    const float* fb3 = (const float*)d_in[8];
    const float* mW1 = (const float*)d_in[9];
    const float* mb1 = (const float*)d_in[10];
    const float* mW2 = (const float*)d_in[11];
    const float* mb2 = (const float*)d_in[12];
    const float* mW3 = (const float*)d_in[13];
    const float* mb3 = (const float*)d_in[14];
    float* out = (float*)d_out;

    float* part   = (float*)d_ws;                      // NN*FF*OO floats = 4 MiB
    float* f_sums = part + (size_t)NN * FF * OO;       // NN*OO floats
    float* bp     = f_sums + (size_t)NN * OO;          // 512 floats
    float* ab     = bp + BPPAD;                        // 2*320 floats

    pwl_setup<<<1, 512, 0, stream>>>(mW1, mb1, mW2, mb2, mW3, mb3, bp, ab);
    fnet_kernel<<<dim3(FF, NN / 256), 256, 0, stream>>>(
        x, fW1, fb1, fW2, fb2, fW3, fb3, part);
    fsum_reduce<<<NN, 64, 0, stream>>>(part, f_sums);
    mnet_pwl<<<NN, 256, 0, stream>>>(nd, nm, f_sums, bp, ab, out);
}

// Round 3
// 47.762 us; speedup vs baseline: 2.6145x; 1.0756x over previous
//
#include <hip/hip_runtime.h>

#define NN 2048
#define FF 64
#define HH 16
#define OO 8

#define BIGF  1e30f
#define BIGTH 1e29f
#define MAXBP 288   // 16 L1 knees + 17*16 layer-2 crossings
#define BPPAD 512   // padded sorted-breakpoint array
#define ABPAD 320   // alpha/beta per segment
#define GCELL 1024  // uniform lookup cells over [-16,16)

// cell index: must be IDENTICAL in setup and mnet
__device__ inline int cell_of(float d)
{
    int k = (int)floorf(fmaf(d, 32.f, 512.f));   // (d+16)*32
    return min(max(k, 0), GCELL - 1);
}
// key for counting: invalid (BIG) entries sort past every cell
__device__ inline int keycell(float v)
{
    return (v > BIGTH) ? GCELL : cell_of(v);
}

// ---------- PWL propagation helpers (validated in round 2, absmax 0.0) ----------
__device__ inline void l1_pattern(float c, const float* w1, const float* b1,
                                  float* a1, float* v1)
{
#pragma unroll
    for (int h = 0; h < HH; ++h) {
        const float arg = fmaf(w1[h], c, b1[h]);
        const bool act = arg > 0.f;
        a1[h] = act ? w1[h] : 0.f;
        v1[h] = act ? b1[h] : 0.f;
    }
}

__device__ inline void l2_arg(float c, int g,
                              const float* w1, const float* b1,
                              const float* w2, const float* b2,
                              float& A, float& B)
{
    float a1[HH], v1[HH];
    l1_pattern(c, w1, b1, a1, v1);
    float Aa = 0.f, Bb = b2[g];
#pragma unroll
    for (int h = 0; h < HH; ++h) {
        Aa = fmaf(w2[g * HH + h], a1[h], Aa);
        Bb = fmaf(w2[g * HH + h], v1[h], Bb);
    }
    A = Aa; B = Bb;
}

__device__ inline void pwl_coeffs(float c,
                                  const float* w1, const float* b1,
                                  const float* w2, const float* b2,
                                  const float* w3, float b3,
                                  float& alpha, float& beta)
{
    float a1[HH], v1[HH];
    l1_pattern(c, w1, b1, a1, v1);
    float al = 0.f, be = b3;
#pragma unroll
    for (int g = 0; g < HH; ++g) {
        float A = 0.f, B = b2[g];
#pragma unroll
        for (int h = 0; h < HH; ++h) {
            A = fmaf(w2[g * HH + h], a1[h], A);
            B = fmaf(w2[g * HH + h], v1[h], B);
        }
        const bool act = fmaf(A, c, B) > 0.f;
        al = fmaf(w3[g], act ? A : 0.f, al);
        be = fmaf(w3[g], act ? B : 0.f, be);
    }
    alpha = al; beta = be;
}

__device__ inline float seg_midpoint(float L, float R)
{
    float c;
    if (L <= -BIGTH && R >= BIGTH) c = 2.5f;
    else if (L <= -BIGTH)          c = R - 1.f;
    else if (R >= BIGTH)           c = L + 1.f;
    else                           c = 0.5f * (L + R);
    return fminf(fmaxf(c, -20.f), 20.f);
}

// ============ Kernel A: fnet (blocks 0..255) + PWL/cell setup (block 256) ============
__global__ __launch_bounds__(512) void setup_kernel(
    const float* __restrict__ x,
    const float* __restrict__ fW1, const float* __restrict__ fb1,
    const float* __restrict__ fW2, const float* __restrict__ fb2,
    const float* __restrict__ fW3, const float* __restrict__ fb3,
    const float* __restrict__ mW1, const float* __restrict__ mb1,
    const float* __restrict__ mW2, const float* __restrict__ mb2,
    const float* __restrict__ mW3, const float* __restrict__ mb3,
    float* __restrict__ part,
    float* __restrict__ bp_out, float* __restrict__ ab_out,
    float* __restrict__ cell4_out, float* __restrict__ cellb_out)
{
    const int tid = threadIdx.x;

    if (blockIdx.x < 256) {
        // ---------------- fnet: f = b&63, node chunk = b>>6 ----------------
        __shared__ float sw1[HH], sb1[HH], sw2[HH * HH], sb2[HH], sw3[OO * HH], sb3[OO];
        const int f = blockIdx.x & 63;

        if (tid < HH) {
            sw1[tid] = fW1[f * HH + tid];
            sb1[tid] = fb1[f * HH + tid];
            sb2[tid] = fb2[f * HH + tid];
        }
        if (tid < HH * HH) sw2[tid] = fW2[f * HH * HH + tid];
        if (tid < OO * HH) sw3[tid] = fW3[f * OO * HH + tid];
        if (tid < OO)      sb3[tid] = fb3[f * OO + tid];
        __syncthreads();

        const int n = (blockIdx.x >> 6) * 512 + tid;
        const float xv = x[n * FF + f];

        float h1[HH];
#pragma unroll
        for (int h = 0; h < HH; ++h)
            h1[h] = fmaxf(fmaf(xv, sw1[h], sb1[h]), 0.f);

        float h2[HH];
#pragma unroll
        for (int g = 0; g < HH; ++g) {
            float a = sb2[g];
#pragma unroll
            for (int h = 0; h < HH; ++h) a = fmaf(sw2[g * HH + h], h1[h], a);
            h2[g] = fmaxf(a, 0.f);
        }

#pragma unroll
        for (int o = 0; o < OO; ++o) {
            float a = sb3[o];
#pragma unroll
            for (int h = 0; h < HH; ++h) a = fmaf(sw3[o * HH + h], h2[h], a);
            part[(n * FF + f) * OO + o] = a;
        }
        return;
    }

    // ---------------- PWL setup (single block) ----------------
    __shared__ float w1[HH], b1[HH], w2[HH * HH], b2[HH], w3[HH];
    __shared__ float b3s;
    __shared__ float ends[18];
    __shared__ float cand[MAXBP];
    __shared__ float sorted[BPPAD];
    __shared__ float t16s[HH];
    __shared__ float sal[ABPAD], sbe[ABPAD];

    if (tid < HH) { w1[tid] = mW1[tid]; b1[tid] = mb1[tid]; b2[tid] = mb2[tid]; w3[tid] = mW3[tid]; }
    if (tid < HH * HH) w2[tid] = mW2[tid];
    if (tid == 0) b3s = mb3[0];
    sorted[tid] = BIGF;                       // 512 threads cover BPPAD
    __syncthreads();

    // layer-1 knees
    if (tid < HH) {
        const float w = w1[tid];
        const float t = -b1[tid] / w;
        cand[tid] = (w != 0.f && t > -10.f && t < 10.f) ? t : BIGF;
    }
    __syncthreads();
    if (tid < HH) {
        const float my = cand[tid];
        int r = 0;
        for (int k = 0; k < HH; ++k) {
            const float o = cand[k];
            r += (o < my) || (o == my && k < tid);
        }
        t16s[r] = my;
    }
    __syncthreads();
    if (tid == 0)  ends[0] = -BIGF;
    if (tid < HH)  ends[tid + 1] = t16s[tid];
    if (tid == 0)  ends[17] = BIGF;
    __syncthreads();

    // layer-2 zero crossings per L1 interval
    if (tid < 17 * HH) {
        const int iv = tid >> 4;
        const int g  = tid & 15;
        const float L = ends[iv], R = ends[iv + 1];
        float xx = BIGF;
        if (L < BIGTH) {
            const float c = seg_midpoint(L, R);
            float A, B;
            l2_arg(c, g, w1, b1, w2, b2, A, B);
            const float t = -B / A;
            if (t > L && t < R && t > -10.f && t < 10.f) xx = t;
        }
        cand[HH + tid] = xx;
    }
    __syncthreads();

    // rank-sort all 288 candidates into sorted[0..287] (rest stay BIGF)
    if (tid < MAXBP) {
        const float my = cand[tid];
        int r = 0;
        for (int k = 0; k < MAXBP; ++k) {
            const float o = cand[k];
            r += (o < my) || (o == my && k < tid);
        }
        sorted[r] = my;
    }
    __syncthreads();

    bp_out[tid] = sorted[tid];

    // per-segment (alpha,beta)
    if (tid < ABPAD) {
        float al = 0.f, be = 0.f;
        if (tid <= MAXBP) {
            const float L = (tid == 0)    ? -BIGF : sorted[tid - 1];
            const float R = (tid < MAXBP) ? sorted[tid] : BIGF;
            const float c = seg_midpoint(L, R);
            pwl_coeffs(c, w1, b1, w2, b2, w3, b3s, al, be);
        }
        sal[tid] = al; sbe[tid] = be;
        ab_out[tid] = al;
        ab_out[ABPAD + tid] = be;
    }
    __syncthreads();

    // per-cell records via binary counting over sorted keys
    for (int k = tid; k < GCELL; k += 512) {
        int base = 0, nxt = 0;
#pragma unroll
        for (int st = 256; st >= 1; st >>= 1) {
            base += (keycell(sorted[base + st - 1]) < k)     ? st : 0;
            nxt  += (keycell(sorted[nxt  + st - 1]) < k + 1) ? st : 0;
        }
        const int cnt = nxt - base;
        float4 r; float bk;
        if (cnt == 0) {
            r.x = sal[base]; r.y = sbe[base]; r.z = r.x; r.w = r.y;
            bk = -BIGF;
        } else {
            const float bmin = sorted[base];
            const float bmax = sorted[nxt - 1];
            if (bmin == bmax) {
                r.x = sal[base];       r.y = sbe[base];
                r.z = sal[base + cnt]; r.w = sbe[base + cnt];
                bk = bmin;
            } else {
                r.x = r.y = r.z = r.w = 0.f;
                bk = __int_as_float(0x7fc00000);   // NaN -> exact fallback
            }
        }
        reinterpret_cast<float4*>(cell4_out)[k] = r;
        cellb_out[k] = bk;
    }
}

// ============ Kernel B: reduce partials over F (wave per node) ============
__global__ __launch_bounds__(256) void fsum_reduce(
    const float* __restrict__ part, float* __restrict__ f_sums)
{
    const int n = blockIdx.x * 4 + (threadIdx.x >> 6);
    const int f = threadIdx.x & 63;
    const float4* p = reinterpret_cast<const float4*>(part + (n * FF + f) * OO);
    float4 a = p[0];
    float4 b = p[1];
#pragma unroll
    for (int off = 32; off > 0; off >>= 1) {
        a.x += __shfl_down(a.x, off, 64);
        a.y += __shfl_down(a.y, off, 64);
        a.z += __shfl_down(a.z, off, 64);
        a.w += __shfl_down(a.w, off, 64);
        b.x += __shfl_down(b.x, off, 64);
        b.y += __shfl_down(b.y, off, 64);
        b.z += __shfl_down(b.z, off, 64);
        b.w += __shfl_down(b.w, off, 64);
    }
    if (f == 0) {
        float4* q = reinterpret_cast<float4*>(f_sums + n * OO);
        q[0] = a;
        q[1] = b;
    }
}

// ============ Kernel C: m via cell table + normalize + matvec (wave per row) ============
__global__ __launch_bounds__(256) void mnet_kernel(
    const float* __restrict__ d, const float* __restrict__ norm,
    const float* __restrict__ f_sums,
    const float* __restrict__ bp_g, const float* __restrict__ ab_g,
    const float* __restrict__ cell4_g, const float* __restrict__ cellb_g,
    float* __restrict__ out)
{
    __shared__ float4 sc4[GCELL];
    __shared__ float  scb[GCELL];
    __shared__ float  sbp[BPPAD], sal[ABPAD], sbe[ABPAD];
    const int tid = threadIdx.x;

    for (int k = tid; k < GCELL; k += 256) {
        sc4[k] = reinterpret_cast<const float4*>(cell4_g)[k];
        scb[k] = cellb_g[k];
    }
    for (int k = tid; k < BPPAD; k += 256) sbp[k] = bp_g[k];
    for (int k = tid; k < ABPAD; k += 256) { sal[k] = ab_g[k]; sbe[k] = ab_g[ABPAD + k]; }
    __syncthreads();

    const int w = tid >> 6;
    const int lane = tid & 63;
    const int i = blockIdx.x * 4 + w;

    const float* drow = d + (size_t)i * NN;
    const float* nrow = norm + (size_t)i * NN;

    float acc[OO];
#pragma unroll
    for (int o = 0; o < OO; ++o) acc[o] = 0.f;

#pragma unroll
    for (int it = 0; it < NN / 256; ++it) {          // 8 iterations
        const int j0 = (it * 64 + lane) * 4;
        const float4 dv4 = *reinterpret_cast<const float4*>(drow + j0);
        const float4 nv4 = *reinterpret_cast<const float4*>(nrow + j0);
        const float dvs[4] = {dv4.x, dv4.y, dv4.z, dv4.w};
        const float nvs[4] = {nv4.x, nv4.y, nv4.z, nv4.w};
#pragma unroll
        for (int e = 0; e < 4; ++e) {
            const float dv = dvs[e];
            const int k = cell_of(dv);
            const float4 r = sc4[k];
            const float bk = scb[k];
            float al = (dv < bk) ? r.x : r.z;
            float be = (dv < bk) ? r.y : r.w;
            if (bk != bk) {                          // NaN marker: exact fallback (rare)
                int lo = 0;
#pragma unroll
                for (int st = 256; st >= 1; st >>= 1)
                    lo += (sbp[lo + st - 1] <= dv) ? st : 0;
                al = sal[lo]; be = sbe[lo];
            }
            const float mn = fmaf(al, dv, be) * __builtin_amdgcn_rcpf(nvs[e]);
            const float4 f0 = *reinterpret_cast<const float4*>(f_sums + (j0 + e) * OO);
            const float4 f1 = *reinterpret_cast<const float4*>(f_sums + (j0 + e) * OO + 4);
            acc[0] = fmaf(mn, f0.x, acc[0]);
            acc[1] = fmaf(mn, f0.y, acc[1]);
            acc[2] = fmaf(mn, f0.z, acc[2]);
            acc[3] = fmaf(mn, f0.w, acc[3]);
            acc[4] = fmaf(mn, f1.x, acc[4]);
            acc[5] = fmaf(mn, f1.y, acc[5]);
            acc[6] = fmaf(mn, f1.z, acc[6]);
            acc[7] = fmaf(mn, f1.w, acc[7]);
        }
    }

#pragma unroll
    for (int off = 32; off > 0; off >>= 1) {
#pragma unroll
        for (int o = 0; o < OO; ++o) acc[o] += __shfl_down(acc[o], off, 64);
    }
    if (lane == 0) {
#pragma unroll
        for (int o = 0; o < OO; ++o) out[i * OO + o] = acc[o];
    }
}

extern "C" void kernel_launch(void* const* d_in, const int* in_sizes, int n_in,
                              void* d_out, int out_size, void* d_ws, size_t ws_size,
                              hipStream_t stream)
{
    const float* x   = (const float*)d_in[0];
    const float* nd  = (const float*)d_in[1];
    const float* nm  = (const float*)d_in[2];
    const float* fW1 = (const float*)d_in[3];
    const float* fb1 = (const float*)d_in[4];
    const float* fW2 = (const float*)d_in[5];
    const float* fb2 = (const float*)d_in[6];
    const float* fW3 = (const float*)d_in[7];
    const float* fb3 = (const float*)d_in[8];
    const float* mW1 = (const float*)d_in[9];
    const float* mb1 = (const float*)d_in[10];
    const float* mW2 = (const float*)d_in[11];
    const float* mb2 = (const float*)d_in[12];
    const float* mW3 = (const float*)d_in[13];
    const float* mb3 = (const float*)d_in[14];
    float* out = (float*)d_out;

    float* part   = (float*)d_ws;                      // NN*FF*OO = 1,048,576 floats
    float* f_sums = part + (size_t)NN * FF * OO;       // 16,384
    float* bp     = f_sums + (size_t)NN * OO;          // 512
    float* ab     = bp + BPPAD;                        // 640
    float* cell4  = ab + 2 * ABPAD;                    // 4096 (1024 float4)
    float* cellb  = cell4 + 4 * GCELL;                 // 1024

    setup_kernel<<<257, 512, 0, stream>>>(
        x, fW1, fb1, fW2, fb2, fW3, fb3,
        mW1, mb1, mW2, mb2, mW3, mb3,
        part, bp, ab, cell4, cellb);
    fsum_reduce<<<512, 256, 0, stream>>>(part, f_sums);
    mnet_kernel<<<512, 256, 0, stream>>>(nd, nm, f_sums, bp, ab, cell4, cellb, out);
}